// Round 4
// baseline (358.744 us; speedup 1.0000x reference)
//
#include <hip/hip_runtime.h>
#include <hip/hip_bf16.h>

// Problem constants (fixed by setup_inputs):
//   B=4, N_down=16384, N_up=65536, C_down=256, C_up=128, C_out=128
// Structure: y = leaky(x_down @ W_lin + b_lin) once per down-row (mlp1_down,
// bf16), then fused_cat = leaky(concat(x_up, gather(y)) @ W_fus + b_fus).
// R4: fused_cat is WAVE-AUTONOMOUS — no LDS, no barriers. Each wave owns a
// 32x128 output tile, reads A-frags directly from global in MFMA layout
// (x_up fp32 -> cvt in reg; y already bf16), B-frags from the L1/L2-hot pack.
// Rationale: R0-R3 all pinned at 2.80 TB/s regardless of structure — the
// barrier convoy capped load-issue duty cycle. Barrier-free waves issue
// loads continuously.
constexpr int N_DOWN = 16384;
constexpr int N_UP   = 65536;
constexpr int BATCH  = 4;
constexpr int M_BLK  = 64;     // rows per tile (mlp1_down)
constexpr int TS     = 264;    // LDS row stride for mlp1_down (256+8 pad)
constexpr int W_ROWS = 32;     // rows per wave (fused_cat)
constexpr int NWAVES = (BATCH * N_UP) / W_ROWS;          // 8192 waves
constexpr int GRID_C = NWAVES / 4;                       // 2048 blocks x 4 waves

typedef __attribute__((ext_vector_type(8))) short short8;   // 8 x bf16 MFMA A/B frag
typedef __attribute__((ext_vector_type(4))) float f32x4;    // MFMA C/D frag

static __device__ inline unsigned short f2b(float f) {
  __hip_bfloat16 h = __float2bfloat16(f);
  return __builtin_bit_cast(unsigned short, h);
}
// fp32x4 -> bf16x4, single 8B LDS store
static __device__ inline void cvt_store4(__hip_bfloat16* dst, float4 v) {
  ushort4 s;
  s.x = f2b(v.x); s.y = f2b(v.y); s.z = f2b(v.z); s.w = f2b(v.w);
  *(ushort4*)dst = s;
}
// 8 fp32 -> bf16x8 A-frag
static __device__ inline short8 cvt8(float4 v0, float4 v1) {
  short8 r;
  r[0] = (short)f2b(v0.x); r[1] = (short)f2b(v0.y);
  r[2] = (short)f2b(v0.z); r[3] = (short)f2b(v0.w);
  r[4] = (short)f2b(v1.x); r[5] = (short)f2b(v1.y);
  r[6] = (short)f2b(v1.z); r[7] = (short)f2b(v1.w);
  return r;
}

// ---------------------------------------------------------------------------
// Repack W_lin / W_fus ([K=256][N=128] row-major fp32) into bf16 MFMA
// B-fragment order: frag (kk*8 + strip), lane holds
//   val[j] = W[kk*32 + (lane>>4)*8 + j][strip*16 + (lane&15)]
// ---------------------------------------------------------------------------
__global__ void repack_w(const float* __restrict__ Wl,
                         const float* __restrict__ Wf,
                         __hip_bfloat16* __restrict__ pack) {
  int t = blockIdx.x * 256 + threadIdx.x;          // 0 .. 8191
  if (t >= 8192) return;
  int lane  = t & 63;
  int strip = (t >> 6) & 7;
  int kk    = (t >> 9) & 7;
  int w     = t >> 12;
  const float* W = w ? Wf : Wl;
  int q = lane >> 4;
  int l = lane & 15;
  int c = strip * 16 + l;
  short8 vals;
#pragma unroll
  for (int j = 0; j < 8; ++j) {
    int k = kk * 32 + q * 8 + j;
    vals[j] = (short)f2b(W[k * 128 + c]);
  }
  *(short8*)(pack + (size_t)t * 8) = vals;
}

// ---------------------------------------------------------------------------
// Kernel A: y[r, :] = leaky(x_down[r, :] @ W_lin + b_lin), bf16 out.
// (unchanged to isolate the fused_cat change)
// ---------------------------------------------------------------------------
__global__ __launch_bounds__(512, 8)
void mlp1_down(const float* __restrict__ x_down,
               const float* __restrict__ b_lin,
               const __hip_bfloat16* __restrict__ pack,
               __hip_bfloat16* __restrict__ y) {
  __shared__ __hip_bfloat16 T[M_BLK * TS];

  const int tid  = threadIdx.x;
  const int wave = tid >> 6;
  const int lane = tid & 63;
  const int q    = lane >> 4;
  const int l    = lane & 15;
  const int m0   = blockIdx.x * M_BLK;   // flat row over BATCH*N_DOWN

  {
    const int lr = tid >> 3;
    const int s8 = tid & 7;
    const float* src = x_down + (size_t)(m0 + lr) * 256;
    __hip_bfloat16* dst = T + lr * TS;
#pragma unroll
    for (int j = 0; j < 8; ++j) {
      int c4 = j * 8 + s8;
      float4 v = *(const float4*)(src + c4 * 4);
      cvt_store4(dst + c4 * 4, v);
    }
  }

  short8 B1[8];
#pragma unroll
  for (int kk = 0; kk < 8; ++kk)
    B1[kk] = *(const short8*)(pack + (size_t)((kk * 8 + wave) * 64 + lane) * 8);
  const float bias1 = b_lin[wave * 16 + l];

  __syncthreads();

  f32x4 acc[4];
#pragma unroll
  for (int rg = 0; rg < 4; ++rg) acc[rg] = f32x4{0.f, 0.f, 0.f, 0.f};
#pragma unroll
  for (int kk = 0; kk < 8; ++kk) {
#pragma unroll
    for (int rg = 0; rg < 4; ++rg) {
      short8 a = *(const short8*)(T + (rg * 16 + l) * TS + kk * 32 + q * 8);
      acc[rg] = __builtin_amdgcn_mfma_f32_16x16x32_bf16(a, B1[kk], acc[rg], 0, 0, 0);
    }
  }

#pragma unroll
  for (int rg = 0; rg < 4; ++rg) {
#pragma unroll
    for (int i = 0; i < 4; ++i) {
      float v = acc[rg][i] + bias1;
      v = (v >= 0.f) ? v : 0.1f * v;
      y[(size_t)(m0 + rg * 16 + q * 4 + i) * 128 + wave * 16 + l] = __float2bfloat16(v);
    }
  }
}

// ---------------------------------------------------------------------------
// Kernel B: out = leaky(concat(x_up, gather(y)) @ W_fus + b_fus).
// Wave-autonomous: each wave computes a 32x128 tile. NO LDS, NO BARRIERS.
//   A-frags (16x16x32 layout: lane holds row l&15, k = (lane>>4)*8+j):
//     kk 0..3 from x_up (fp32, 2x float4 + cvt), kk 4..7 from gathered y
//     (bf16, one dwordx4 = 16 random rows x fully-used 64B lines).
//   B-frags: reloaded per use from pack (L1/L2-hot; R1's VGPR=28 showed the
//   compiler prefers this anyway).
// ---------------------------------------------------------------------------
__global__ __launch_bounds__(256, 4)
void fused_cat(const float* __restrict__ x_up,
               const int* __restrict__ up_idx,
               const __hip_bfloat16* __restrict__ y,
               const float* __restrict__ b_fus,
               const __hip_bfloat16* __restrict__ pack,
               float* __restrict__ out) {
  const int tid  = threadIdx.x;
  const int wave = tid >> 6;
  const int lane = tid & 63;
  const int q    = lane >> 4;
  const int l    = lane & 15;

  const int gw = blockIdx.x * 4 + wave;     // global wave id
  const int m0 = gw * W_ROWS;               // first row of this wave's tile
  const int b  = m0 >> 16;                  // batch (2048 tiles/batch: no straddle)
  const __hip_bfloat16* ybase = y + (size_t)b * (N_DOWN * 128);
  const __hip_bfloat16* packF = pack + 4096 * 8;    // W_fus fragment block

  // gather indices for the two 16-row groups (broadcast across q)
  const int i0 = up_idx[m0 + l];
  const int i1 = up_idx[m0 + 16 + l];

  f32x4 acc[2][8];
#pragma unroll
  for (int rg = 0; rg < 2; ++rg)
#pragma unroll
    for (int s = 0; s < 8; ++s) acc[rg][s] = f32x4{0.f, 0.f, 0.f, 0.f};

  // ---- K 0..127: x_up (direct from global, fp32 -> bf16 in reg) ----
#pragma unroll
  for (int kk = 0; kk < 4; ++kk) {
    short8 a[2];
#pragma unroll
    for (int rg = 0; rg < 2; ++rg) {
      const float* p = x_up + (size_t)(m0 + rg * 16 + l) * 128 + kk * 32 + q * 8;
      float4 v0 = *(const float4*)p;
      float4 v1 = *(const float4*)(p + 4);
      a[rg] = cvt8(v0, v1);
    }
#pragma unroll
    for (int s = 0; s < 8; ++s) {
      short8 Bf = *(const short8*)(packF + (size_t)((kk * 8 + s) * 64 + lane) * 8);
      acc[0][s] = __builtin_amdgcn_mfma_f32_16x16x32_bf16(a[0], Bf, acc[0][s], 0, 0, 0);
      acc[1][s] = __builtin_amdgcn_mfma_f32_16x16x32_bf16(a[1], Bf, acc[1][s], 0, 0, 0);
    }
  }

  // ---- K 128..255: gathered y (already bf16: one 16B load per frag) ----
#pragma unroll
  for (int kk = 0; kk < 4; ++kk) {
    short8 a0 = *(const short8*)(ybase + (size_t)i0 * 128 + kk * 32 + q * 8);
    short8 a1 = *(const short8*)(ybase + (size_t)i1 * 128 + kk * 32 + q * 8);
#pragma unroll
    for (int s = 0; s < 8; ++s) {
      short8 Bf = *(const short8*)(packF + (size_t)(((kk + 4) * 8 + s) * 64 + lane) * 8);
      acc[0][s] = __builtin_amdgcn_mfma_f32_16x16x32_bf16(a0, Bf, acc[0][s], 0, 0, 0);
      acc[1][s] = __builtin_amdgcn_mfma_f32_16x16x32_bf16(a1, Bf, acc[1][s], 0, 0, 0);
    }
  }

  // ---- epilogue: bias + leaky -> fp32 out ----
#pragma unroll
  for (int s = 0; s < 8; ++s) {
    const float bs = b_fus[s * 16 + l];
#pragma unroll
    for (int rg = 0; rg < 2; ++rg) {
#pragma unroll
      for (int i = 0; i < 4; ++i) {
        float v = acc[rg][s][i] + bs;
        v = (v >= 0.f) ? v : 0.1f * v;
        out[(size_t)(m0 + rg * 16 + q * 4 + i) * 128 + s * 16 + l] = v;
      }
    }
  }
}

extern "C" void kernel_launch(void* const* d_in, const int* in_sizes, int n_in,
                              void* d_out, int out_size, void* d_ws, size_t ws_size,
                              hipStream_t stream) {
  const float* x_down = (const float*)d_in[0];
  const float* x_up   = (const float*)d_in[1];
  const int*   up_idx = (const int*)d_in[2];
  const float* W_lin  = (const float*)d_in[3];
  const float* b_lin  = (const float*)d_in[4];
  const float* W_fus  = (const float*)d_in[5];
  const float* b_fus  = (const float*)d_in[6];
  float* out = (float*)d_out;

  // workspace layout: [0, 128 KiB) weight pack, [128 KiB, +16 MiB) y (bf16)
  __hip_bfloat16* pack = (__hip_bfloat16*)d_ws;
  __hip_bfloat16* y    = (__hip_bfloat16*)((char*)d_ws + 131072);

  repack_w<<<32, 256, 0, stream>>>(W_lin, W_fus, pack);
  mlp1_down<<<(BATCH * N_DOWN) / M_BLK, 512, 0, stream>>>(x_down, b_lin, pack, y);
  fused_cat<<<GRID_C, 256, 0, stream>>>(x_up, up_idx, y, b_fus, pack, out);
}